// Round 9
// baseline (160.420 us; speedup 1.0000x reference)
//
#include <hip/hip_runtime.h>
#include <hip/hip_bf16.h>

#define NN 50000
#define NE 500000
#define C 128
#define NBLK ((NN + 255) / 256)       // 196 scan blocks
#define HISTB ((NE + 255) / 256)      // 1954 hist blocks
#define SPB (NN / 8)                  // 6250 spmm blocks (exact: 50000 = 6250*8)
#define RB 128                        // reduce1 blocks
#define RROWS ((SPB + RB - 1) / RB)   // 49 rows per reduce1 block
#define GB ((NN + 63) / 64)           // 782 gemm blocks
#define BN_EPS 1e-5f
#define NEG 0.01f
#define WSCALE 16777216.0f            // 2^24 fixed-point for packed degree
#define WMASK  0xFFFFFFFFFFFULL      // low 44 bits

typedef __attribute__((ext_vector_type(8))) short bf16x8;
typedef __attribute__((ext_vector_type(4))) float f32x4;

// bf16 helpers
__device__ inline unsigned short f2bf(float f) {            // round-to-nearest-even
    unsigned int u = __float_as_uint(f);
    unsigned int r = (u + 0x7fffu + ((u >> 16) & 1u)) >> 16;
    return (unsigned short)r;
}
__device__ inline unsigned int pack2(float a, float b) {
    return (unsigned int)f2bf(a) | ((unsigned int)f2bf(b) << 16);
}
__device__ inline float4 bf4_to_f4(uint2 u) {               // 4 packed bf16 -> 4 f32
    float4 r;
    r.x = __uint_as_float(u.x << 16);
    r.y = __uint_as_float(u.x & 0xffff0000u);
    r.z = __uint_as_float(u.y << 16);
    r.w = __uint_as_float(u.y & 0xffff0000u);
    return r;
}

// ---------------- setup: zero hist+counter | wprep | cvec (one dispatch) ----------------
// blocks 0..127: zero; block 128: wprep; block 129: cvec
__global__ __launch_bounds__(256) void setup_kernel(const float* __restrict__ Wg,
                                                    const float* __restrict__ Wl,
                                                    unsigned int* __restrict__ Wgt,
                                                    unsigned int* __restrict__ Wlt,
                                                    const float* __restrict__ td,
                                                    const float* __restrict__ mf,
                                                    float* __restrict__ cvec,
                                                    float* __restrict__ zreg) {
    const int b = blockIdx.x;
    const int t = threadIdx.x;
    if (b < 128) {
        long i = (long)b * 256 + t;
        const long n = 2L * NN + 4;        // hist (NN u64) + counter
        const long s = 128L * 256;
        for (; i < n; i += s) zreg[i] = 0.f;
    } else if (b == 128) {
        // W[k][c] f32 -> Wt[c][ku] bf16 pairs, linear layout (L1-served, no LDS)
        const int col = t >> 1;
        const int half = t & 1;
        for (int j = 0; j < 32; j++) {
            int ku = half * 32 + j;
            int k0 = 2 * ku;
            unsigned int slot = (unsigned int)col * 64u + (unsigned int)ku;
            Wgt[slot] = pack2(Wg[(size_t)k0 * C + col], Wg[(size_t)(k0 + 1) * C + col]);
            Wlt[slot] = pack2(Wl[(size_t)k0 * C + col], Wl[(size_t)(k0 + 1) * C + col]);
        }
    } else {
        if (t < 128) {
            float tv = td[0];
            float acc = 0.f;
#pragma unroll
            for (int j = 0; j < 16; j++) {
                float s = sinf(tv * mf[j] * 3.14159265358979323846f);
                acc = fmaf(s, Wg[(128 + j) * C + t], acc);
            }
            cvec[t] = acc;
        }
    }
}

// ---------------- mega1: hist blocks (0..HISTB) then GEMM1 blocks — NO LDS ----------------
__global__ __launch_bounds__(256) void mega1_kernel(const float* __restrict__ X,
                                                    const unsigned int* __restrict__ Wt,
                                                    const float* __restrict__ cvec,
                                                    unsigned short* __restrict__ Hb,
                                                    const int* __restrict__ ei,
                                                    const float* __restrict__ ew,
                                                    unsigned long long* __restrict__ hist,
                                                    int* __restrict__ rank) {
    const int bid = blockIdx.x;
    const int t = threadIdx.x;
    if (bid < HISTB) {
        int e = bid * 256 + t;
        if (e < NE) {
            int c = ei[NE + e];
            unsigned long long pack = (1ULL << 44) | (unsigned long long)(ew[e] * WSCALE);
            unsigned long long old = atomicAdd(&hist[c], pack);
            rank[e] = (int)(old >> 44);
        }
        return;
    }
    const int gb = bid - HISTB;
    const int lane = t & 63;
    const int wid = t >> 6;
    const int lrow = lane & 15;
    const int kb = lane >> 4;            // 0..3
    const int row = gb * 64 + wid * 16 + lrow;
    const float* xrow = X + (size_t)min(row, NN - 1) * C;

    f32x4 acc[8];
#pragma unroll
    for (int n = 0; n < 8; n++) acc[n] = (f32x4){0.f, 0.f, 0.f, 0.f};

#pragma unroll
    for (int ks = 0; ks < 4; ks++) {
        float4 a0 = *(const float4*)(xrow + ks * 32 + kb * 8);
        float4 a1 = *(const float4*)(xrow + ks * 32 + kb * 8 + 4);
        union { unsigned int u[4]; bf16x8 v; } af;
        af.u[0] = pack2(a0.x, a0.y); af.u[1] = pack2(a0.z, a0.w);
        af.u[2] = pack2(a1.x, a1.y); af.u[3] = pack2(a1.z, a1.w);
        const int ko = (ks * 4 + kb) * 4;
#pragma unroll
        for (int n = 0; n < 8; n++) {
            int col = n * 16 + lrow;
            union { uint4 q; bf16x8 v; } bfm;
            bfm.q = *(const uint4*)&Wt[col * 64 + ko];     // L1-resident (32 KB total)
            acc[n] = __builtin_amdgcn_mfma_f32_16x16x32_bf16(af.v, bfm.v, acc[n], 0, 0, 0);
        }
    }
    const int orow = gb * 64 + wid * 16 + kb * 4;   // C/D: col=lane&15, row=(lane>>4)*4+i
#pragma unroll
    for (int n = 0; n < 8; n++) {
        int col = n * 16 + lrow;
        float cv = cvec[col];
#pragma unroll
        for (int i = 0; i < 4; i++) {
            int r = orow + i;
            if (r < NN) Hb[(size_t)r * C + col] = f2bf(acc[n][i] + cv);
        }
    }
}

// ---------------- scan pass 1: per-block exclusive scan of decoded counts ----------------
__global__ __launch_bounds__(256) void scanp1_kernel(const unsigned long long* __restrict__ hist,
                                                     int* __restrict__ rptr,
                                                     int* __restrict__ bsum) {
    __shared__ int s[256];
    const int t = threadIdx.x;
    const int i = blockIdx.x * 256 + t;
    int v = (i < NN) ? (int)(hist[i] >> 44) : 0;
    s[t] = v;
    __syncthreads();
    for (int off = 1; off < 256; off <<= 1) {
        int add = (t >= off) ? s[t - off] : 0;
        __syncthreads();
        s[t] += add;
        __syncthreads();
    }
    if (i < NN) rptr[i] = s[t] - v;           // exclusive within block
    if (t == 255) bsum[blockIdx.x] = s[255];  // block total
}

// ---------------- scan pass 2 (fused): block offset = sum(bsum[0..b-1]); + dinv ----------------
__global__ __launch_bounds__(256) void scanp3_kernel(int* __restrict__ rptr,
                                                     const int* __restrict__ bsum,
                                                     const unsigned long long* __restrict__ hist,
                                                     float* __restrict__ dinv) {
    __shared__ int sb[256];
    const int t = threadIdx.x;
    const int b = blockIdx.x;
    sb[t] = (t < NBLK && t < b) ? bsum[t] : 0;
    __syncthreads();
    for (int off = 128; off > 0; off >>= 1) {
        if (t < off) sb[t] += sb[t + off];
        __syncthreads();
    }
    const int boff = sb[0];
    const int i = b * 256 + t;
    if (i < NN) {
        rptr[i] += boff;
        float degw = (float)(hist[i] & WMASK) * (1.0f / WSCALE);
        dinv[i] = rsqrtf(degw + 1.0f);   // +1 self-loop; always > 0
    }
    if (b == 0 && t == 0) rptr[NN] = NE; // total is a constant
}

// ---------------- fill CSR: no atomic — slot = rptr[c] + rank[e] ----------------
__global__ void fill_kernel(const int* __restrict__ ei, const float* __restrict__ ew,
                            const float* __restrict__ dinv, const int* __restrict__ rptr,
                            const int* __restrict__ rank, int2* __restrict__ csr) {
    int e = blockIdx.x * blockDim.x + threadIdx.x;
    if (e >= NE) return;
    int r = ei[e], c = ei[NE + e];
    int slot = rptr[c] + rank[e];
    float w = dinv[r] * ew[e] * dinv[c];
    csr[slot] = make_int2(r, __float_as_int(w));
}

// ---------------- SpMM (bf16 gather, f32 accum, unroll-4) + fused BN partials ----------------
__global__ __launch_bounds__(256) void spmm_kernel(const int* __restrict__ rptr,
                                                   const int2* __restrict__ csr,
                                                   const unsigned short* __restrict__ Hb,
                                                   const float* __restrict__ dinv,
                                                   const float* __restrict__ bg,
                                                   float* __restrict__ OUT,
                                                   float* __restrict__ P) {
    const int nl = threadIdx.x >> 5;                 // node lane 0..7
    const int lane = threadIdx.x & 31;               // channel-group lane
    const int node = blockIdx.x * 8 + nl;            // NN == gridDim*8 exactly
    const int ch = lane * 4;
    int s = rptr[node], e = rptr[node + 1];
    float d = dinv[node];
    float dd = d * d;
    float4 h = bf4_to_f4(*(const uint2*)(Hb + (size_t)node * C + ch));
    float4 acc = make_float4(dd * h.x, dd * h.y, dd * h.z, dd * h.w);
    float4 accB = make_float4(0.f, 0.f, 0.f, 0.f);
    int j = s;
    for (; j + 4 <= e; j += 4) {
        int2 e0 = csr[j], e1 = csr[j + 1], e2 = csr[j + 2], e3 = csr[j + 3];
        float w0 = __int_as_float(e0.y), w1 = __int_as_float(e1.y);
        float w2 = __int_as_float(e2.y), w3 = __int_as_float(e3.y);
        uint2 u0 = *(const uint2*)(Hb + (size_t)e0.x * C + ch);
        uint2 u1 = *(const uint2*)(Hb + (size_t)e1.x * C + ch);
        uint2 u2 = *(const uint2*)(Hb + (size_t)e2.x * C + ch);
        uint2 u3 = *(const uint2*)(Hb + (size_t)e3.x * C + ch);
        float4 v0 = bf4_to_f4(u0), v1 = bf4_to_f4(u1), v2 = bf4_to_f4(u2), v3 = bf4_to_f4(u3);
        acc.x = fmaf(v0.x, w0, acc.x);  acc.y = fmaf(v0.y, w0, acc.y);
        acc.z = fmaf(v0.z, w0, acc.z);  acc.w = fmaf(v0.w, w0, acc.w);
        accB.x = fmaf(v1.x, w1, accB.x); accB.y = fmaf(v1.y, w1, accB.y);
        accB.z = fmaf(v1.z, w1, accB.z); accB.w = fmaf(v1.w, w1, accB.w);
        acc.x = fmaf(v2.x, w2, acc.x);  acc.y = fmaf(v2.y, w2, acc.y);
        acc.z = fmaf(v2.z, w2, acc.z);  acc.w = fmaf(v2.w, w2, acc.w);
        accB.x = fmaf(v3.x, w3, accB.x); accB.y = fmaf(v3.y, w3, accB.y);
        accB.z = fmaf(v3.z, w3, accB.z); accB.w = fmaf(v3.w, w3, accB.w);
    }
    for (; j < e; j++) {
        int2 e0 = csr[j];
        float w0 = __int_as_float(e0.y);
        float4 v0 = bf4_to_f4(*(const uint2*)(Hb + (size_t)e0.x * C + ch));
        acc.x = fmaf(v0.x, w0, acc.x); acc.y = fmaf(v0.y, w0, acc.y);
        acc.z = fmaf(v0.z, w0, acc.z); acc.w = fmaf(v0.w, w0, acc.w);
    }
    acc.x += accB.x; acc.y += accB.y; acc.z += accB.z; acc.w += accB.w;
    float4 b = *(const float4*)(bg + ch);
    acc.x += b.x; acc.y += b.y; acc.z += b.z; acc.w += b.w;
    *(float4*)(OUT + (size_t)node * C + ch) = acc;

    // ---- fused BN partials: reduce over the block's 8 nodes, no atomics ----
    __shared__ __align__(16) float4 sred[2][8][32];   // 8 KiB
    float4 sq = make_float4(acc.x * acc.x, acc.y * acc.y, acc.z * acc.z, acc.w * acc.w);
    sred[0][nl][lane] = acc;
    sred[1][nl][lane] = sq;
    __syncthreads();
    if (nl == 0) {
        float4 s0 = sred[0][0][lane], q0 = sred[1][0][lane];
#pragma unroll
        for (int k = 1; k < 8; k++) {
            float4 a = sred[0][k][lane];
            float4 q = sred[1][k][lane];
            s0.x += a.x; s0.y += a.y; s0.z += a.z; s0.w += a.w;
            q0.x += q.x; q0.y += q.y; q0.z += q.z; q0.w += q.w;
        }
        float* row = P + (size_t)blockIdx.x * 256;
        *(float4*)(row + ch) = s0;
        *(float4*)(row + 128 + ch) = q0;
    }
}

// ---------------- reduce1 + fused bnparam (last-block pattern) ----------------
__global__ __launch_bounds__(256) void reduce1_kernel(const float* __restrict__ P,
                                                      float* __restrict__ P2,
                                                      unsigned int* __restrict__ cnt,
                                                      const float* __restrict__ gm,
                                                      const float* __restrict__ bt,
                                                      float* __restrict__ sc,
                                                      float* __restrict__ sh) {
    const int c = threadIdx.x;
    const int r0 = blockIdx.x * RROWS;
    const int r1 = min(r0 + RROWS, SPB);
    float a0 = 0.f, a1 = 0.f, a2 = 0.f, a3 = 0.f;
    int r = r0;
    for (; r + 4 <= r1; r += 4) {
        a0 += P[(size_t)(r + 0) * 256 + c];
        a1 += P[(size_t)(r + 1) * 256 + c];
        a2 += P[(size_t)(r + 2) * 256 + c];
        a3 += P[(size_t)(r + 3) * 256 + c];
    }
    for (; r < r1; r++) a0 += P[(size_t)r * 256 + c];
    P2[(size_t)blockIdx.x * 256 + c] = (a0 + a1) + (a2 + a3);

    __threadfence();
    __shared__ unsigned int done;
    if (c == 0) done = atomicAdd(cnt, 1u);
    __syncthreads();
    if (done == RB - 1) {
        __threadfence();   // acquire: see all P2 rows
        if (c < 128) {
            float s0 = 0.f, s1 = 0.f, q0 = 0.f, q1 = 0.f;
            for (int k = 0; k < RB; k += 2) {
                s0 += P2[(size_t)k * 256 + c];
                q0 += P2[(size_t)k * 256 + 128 + c];
                s1 += P2[(size_t)(k + 1) * 256 + c];
                q1 += P2[(size_t)(k + 1) * 256 + 128 + c];
            }
            float ssum = s0 + s1, ssq = q0 + q1;
            float mean = ssum / (float)NN;
            float var = ssq / (float)NN - mean * mean;
            var = fmaxf(var, 0.f);
            float rs = rsqrtf(var + BN_EPS);
            float s = gm[c] * rs;
            sc[c] = s;
            sh[c] = bt[c] - mean * s;
        }
    }
}

// ---------------- final (MFMA): y = lrelu(BN(h)) @ W_lin + b_lin, in-place — NO LDS ----------------
__global__ __launch_bounds__(256) void final_kernel(float* __restrict__ OUT,
                                                    const unsigned int* __restrict__ Wt,
                                                    const float* __restrict__ bl,
                                                    const float* __restrict__ sc,
                                                    const float* __restrict__ sh) {
    const int t = threadIdx.x;
    const int lane = t & 63;
    const int wid = t >> 6;
    const int lrow = lane & 15;
    const int kb = lane >> 4;
    const int row = blockIdx.x * 64 + wid * 16 + lrow;
    const float* hrow = OUT + (size_t)min(row, NN - 1) * C;

    f32x4 acc[8];
#pragma unroll
    for (int n = 0; n < 8; n++) acc[n] = (f32x4){0.f, 0.f, 0.f, 0.f};

#pragma unroll
    for (int ks = 0; ks < 4; ks++) {
        const int k0 = ks * 32 + kb * 8;
        float4 v0 = *(const float4*)(hrow + k0);
        float4 v1 = *(const float4*)(hrow + k0 + 4);
        float4 s0 = *(const float4*)(sc + k0);
        float4 s1 = *(const float4*)(sc + k0 + 4);
        float4 h0 = *(const float4*)(sh + k0);
        float4 h1 = *(const float4*)(sh + k0 + 4);
        float a[8];
        a[0] = fmaf(v0.x, s0.x, h0.x); a[1] = fmaf(v0.y, s0.y, h0.y);
        a[2] = fmaf(v0.z, s0.z, h0.z); a[3] = fmaf(v0.w, s0.w, h0.w);
        a[4] = fmaf(v1.x, s1.x, h1.x); a[5] = fmaf(v1.y, s1.y, h1.y);
        a[6] = fmaf(v1.z, s1.z, h1.z); a[7] = fmaf(v1.w, s1.w, h1.w);
#pragma unroll
        for (int i = 0; i < 8; i++) a[i] = a[i] >= 0.f ? a[i] : NEG * a[i];
        union { unsigned int u[4]; bf16x8 v; } af;
        af.u[0] = pack2(a[0], a[1]); af.u[1] = pack2(a[2], a[3]);
        af.u[2] = pack2(a[4], a[5]); af.u[3] = pack2(a[6], a[7]);
        const int ko = (ks * 4 + kb) * 4;
#pragma unroll
        for (int n = 0; n < 8; n++) {
            int col = n * 16 + lrow;
            union { uint4 q; bf16x8 v; } bfm;
            bfm.q = *(const uint4*)&Wt[col * 64 + ko];     // L1-resident
            acc[n] = __builtin_amdgcn_mfma_f32_16x16x32_bf16(af.v, bfm.v, acc[n], 0, 0, 0);
        }
    }
    const int orow = blockIdx.x * 64 + wid * 16 + kb * 4;
#pragma unroll
    for (int n = 0; n < 8; n++) {
        int col = n * 16 + lrow;
        float blv = bl[col];
#pragma unroll
        for (int i = 0; i < 4; i++) {
            int r = orow + i;
            if (r < NN) OUT[(size_t)r * C + col] = acc[n][i] + blv;
        }
    }
}

extern "C" void kernel_launch(void* const* d_in, const int* in_sizes, int n_in,
                              void* d_out, int out_size, void* d_ws, size_t ws_size,
                              hipStream_t stream) {
    const float* x  = (const float*)d_in[0];
    const int*   ei = (const int*)d_in[1];
    const float* ew = (const float*)d_in[2];
    const float* td = (const float*)d_in[3];
    const float* mf = (const float*)d_in[4];
    const float* Wg = (const float*)d_in[5];
    const float* bg = (const float*)d_in[6];
    const float* gm = (const float*)d_in[7];
    const float* bt = (const float*)d_in[8];
    const float* Wl = (const float*)d_in[9];
    const float* bl = (const float*)d_in[10];
    float* out = (float*)d_out;

    // workspace layout (all chunk sizes are multiples of 16 B)
    unsigned short* h1b = (unsigned short*)d_ws;         // NN*C bf16 (12.8 MB)
    unsigned long long* hist = (unsigned long long*)(h1b + (size_t)NN * C);  // NN u64 [zeroed]
    unsigned int* cnt = (unsigned int*)(hist + NN);      // 4 u32 [zeroed]
    float* dinv   = (float*)(cnt + 4);                   // NN
    float* cvec   = dinv + NN;                           // C
    float* sc     = cvec + C;                            // C
    float* sh     = sc + C;                              // C
    int*   rptr   = (int*)(sh + C);                      // NN+8
    int*   bsum   = rptr + NN + 8;                       // 196 (+pad)
    int*   rank   = bsum + NBLK + 12;                    // NE
    int2*  csr    = (int2*)(rank + NE);                  // NE int2
    float* P      = (float*)(csr + NE);                  // SPB*256 (6.4 MB)
    float* P2     = P + (size_t)SPB * 256;               // RB*256
    unsigned int* Wgt = (unsigned int*)(P2 + RB * 256);  // 8192 u32 (32 KB)
    unsigned int* Wlt = Wgt + 8192;                      // 8192 u32 (32 KB)

    setup_kernel<<<130, 256, 0, stream>>>(Wg, Wl, Wgt, Wlt, td, mf, cvec, (float*)hist);
    mega1_kernel<<<HISTB + GB, 256, 0, stream>>>(x, Wgt, cvec, h1b, ei, ew, hist, rank);
    scanp1_kernel<<<NBLK, 256, 0, stream>>>(hist, rptr, bsum);
    scanp3_kernel<<<NBLK, 256, 0, stream>>>(rptr, bsum, hist, dinv);
    fill_kernel<<<HISTB, 256, 0, stream>>>(ei, ew, dinv, rptr, rank, csr);
    spmm_kernel<<<SPB, 256, 0, stream>>>(rptr, csr, h1b, dinv, bg, out, P);
    reduce1_kernel<<<RB, 256, 0, stream>>>(P, P2, cnt, gm, bt, sc, sh);
    final_kernel<<<GB, 256, 0, stream>>>(out, Wlt, bl, sc, sh);
}

// Round 10
// 145.838 us; speedup vs baseline: 1.1000x; 1.1000x over previous
//
#include <hip/hip_runtime.h>
#include <hip/hip_bf16.h>

#define NN 50000
#define NE 500000
#define C 128
#define NBLK ((NN + 255) / 256)       // 196 scan blocks
#define HISTB ((NE + 255) / 256)      // 1954 hist blocks
#define SPB (NN / 8)                  // 6250 spmm blocks (exact: 50000 = 6250*8)
#define RB 128                        // reduce1 blocks
#define RROWS ((SPB + RB - 1) / RB)   // 49 rows per reduce1 block
#define GB ((NN + 63) / 64)           // 782 gemm blocks
#define BN_EPS 1e-5f
#define NEG 0.01f
#define WSCALE 16777216.0f            // 2^24 fixed-point for packed degree
#define WMASK  0xFFFFFFFFFFFULL      // low 44 bits

typedef __attribute__((ext_vector_type(8))) short bf16x8;
typedef __attribute__((ext_vector_type(4))) float f32x4;

// bf16 helpers
__device__ inline unsigned short f2bf(float f) {            // round-to-nearest-even
    unsigned int u = __float_as_uint(f);
    unsigned int r = (u + 0x7fffu + ((u >> 16) & 1u)) >> 16;
    return (unsigned short)r;
}
__device__ inline unsigned int pack2(float a, float b) {
    return (unsigned int)f2bf(a) | ((unsigned int)f2bf(b) << 16);
}
__device__ inline float4 bf4_to_f4(uint2 u) {               // 4 packed bf16 -> 4 f32
    float4 r;
    r.x = __uint_as_float(u.x << 16);
    r.y = __uint_as_float(u.x & 0xffff0000u);
    r.z = __uint_as_float(u.y << 16);
    r.w = __uint_as_float(u.y & 0xffff0000u);
    return r;
}

// ---------------- setup: zero hist+counter | wprep (swizzled) | cvec ----------------
// blocks 0..127: zero; block 128: wprep; block 129: cvec
__global__ __launch_bounds__(256) void setup_kernel(const float* __restrict__ Wg,
                                                    const float* __restrict__ Wl,
                                                    unsigned int* __restrict__ Wgt,
                                                    unsigned int* __restrict__ Wlt,
                                                    const float* __restrict__ td,
                                                    const float* __restrict__ mf,
                                                    float* __restrict__ cvec,
                                                    float* __restrict__ zreg) {
    const int b = blockIdx.x;
    const int t = threadIdx.x;
    if (b < 128) {
        long i = (long)b * 256 + t;
        const long n = 2L * NN + 4;        // hist (NN u64) + counter
        const long s = 128L * 256;
        for (; i < n; i += s) zreg[i] = 0.f;
    } else if (b == 128) {
        // W[k][c] f32 -> Wt[c][ku] bf16 pairs, 16B-granule XOR swizzle (for LDS b128 reads)
        const int col = t >> 1;
        const int half = t & 1;
        for (int j = 0; j < 32; j++) {
            int ku = half * 32 + j;
            int k0 = 2 * ku;
            unsigned int g = (unsigned int)((ku >> 2) ^ (col & 15));
            unsigned int slot = (unsigned int)col * 64u + (g << 2) + (unsigned int)(ku & 3);
            Wgt[slot] = pack2(Wg[(size_t)k0 * C + col], Wg[(size_t)(k0 + 1) * C + col]);
            Wlt[slot] = pack2(Wl[(size_t)k0 * C + col], Wl[(size_t)(k0 + 1) * C + col]);
        }
    } else {
        if (t < 128) {
            float tv = td[0];
            float acc = 0.f;
#pragma unroll
            for (int j = 0; j < 16; j++) {
                float s = sinf(tv * mf[j] * 3.14159265358979323846f);
                acc = fmaf(s, Wg[(128 + j) * C + t], acc);
            }
            cvec[t] = acc;
        }
    }
}

// ---------------- packed histogram + per-edge rank (standalone: 4 VGPR, high occupancy) ----------------
__global__ void hist_kernel(const int* __restrict__ ei, const float* __restrict__ ew,
                            unsigned long long* __restrict__ hist, int* __restrict__ rank) {
    int e = blockIdx.x * blockDim.x + threadIdx.x;
    if (e < NE) {
        int c = ei[NE + e];
        unsigned long long pack = (1ULL << 44) | (unsigned long long)(ew[e] * WSCALE);
        unsigned long long old = atomicAdd(&hist[c], pack);
        rank[e] = (int)(old >> 44);
    }
}

// ---------------- GEMM1 (MFMA, LDS-staged B): h1b = bf16(x @ Wg[0:128,:] + cvec) ----------------
__global__ __launch_bounds__(256) void gemm1_kernel(const float* __restrict__ X,
                                                    const unsigned int* __restrict__ Wt,
                                                    const float* __restrict__ cvec,
                                                    unsigned short* __restrict__ Hb) {
    __shared__ unsigned int wsh[8192];   // 32 KB, swizzled [col][ku]
    const int t = threadIdx.x;
#pragma unroll
    for (int i = 0; i < 8; i++)
        ((uint4*)wsh)[t + i * 256] = ((const uint4*)Wt)[t + i * 256];

    const int lane = t & 63;
    const int wid = t >> 6;
    const int lrow = lane & 15;
    const int kb = lane >> 4;            // 0..3
    const int row = blockIdx.x * 64 + wid * 16 + lrow;
    const float* xrow = X + (size_t)min(row, NN - 1) * C;

    f32x4 acc[8];
#pragma unroll
    for (int n = 0; n < 8; n++) acc[n] = (f32x4){0.f, 0.f, 0.f, 0.f};
    __syncthreads();

#pragma unroll
    for (int ks = 0; ks < 4; ks++) {
        float4 a0 = *(const float4*)(xrow + ks * 32 + kb * 8);
        float4 a1 = *(const float4*)(xrow + ks * 32 + kb * 8 + 4);
        union { unsigned int u[4]; bf16x8 v; } af;
        af.u[0] = pack2(a0.x, a0.y); af.u[1] = pack2(a0.z, a0.w);
        af.u[2] = pack2(a1.x, a1.y); af.u[3] = pack2(a1.z, a1.w);
        const unsigned int gp = (unsigned int)((ks * 4 + kb) ^ lrow);
#pragma unroll
        for (int n = 0; n < 8; n++) {
            int col = n * 16 + lrow;
            union { uint4 q; bf16x8 v; } bfm;
            bfm.q = *(const uint4*)&wsh[col * 64 + gp * 4];
            acc[n] = __builtin_amdgcn_mfma_f32_16x16x32_bf16(af.v, bfm.v, acc[n], 0, 0, 0);
        }
    }
    const int orow = blockIdx.x * 64 + wid * 16 + kb * 4;   // C/D: col=lane&15, row=(lane>>4)*4+i
#pragma unroll
    for (int n = 0; n < 8; n++) {
        int col = n * 16 + lrow;
        float cv = cvec[col];
#pragma unroll
        for (int i = 0; i < 4; i++) {
            int r = orow + i;
            if (r < NN) Hb[(size_t)r * C + col] = f2bf(acc[n][i] + cv);
        }
    }
}

// ---------------- scan pass 1: per-block exclusive scan of decoded counts ----------------
__global__ __launch_bounds__(256) void scanp1_kernel(const unsigned long long* __restrict__ hist,
                                                     int* __restrict__ rptr,
                                                     int* __restrict__ bsum) {
    __shared__ int s[256];
    const int t = threadIdx.x;
    const int i = blockIdx.x * 256 + t;
    int v = (i < NN) ? (int)(hist[i] >> 44) : 0;
    s[t] = v;
    __syncthreads();
    for (int off = 1; off < 256; off <<= 1) {
        int add = (t >= off) ? s[t - off] : 0;
        __syncthreads();
        s[t] += add;
        __syncthreads();
    }
    if (i < NN) rptr[i] = s[t] - v;           // exclusive within block
    if (t == 255) bsum[blockIdx.x] = s[255];  // block total
}

// ---------------- scan pass 2 (fused): block offset = sum(bsum[0..b-1]); + dinv ----------------
__global__ __launch_bounds__(256) void scanp3_kernel(int* __restrict__ rptr,
                                                     const int* __restrict__ bsum,
                                                     const unsigned long long* __restrict__ hist,
                                                     float* __restrict__ dinv) {
    __shared__ int sb[256];
    const int t = threadIdx.x;
    const int b = blockIdx.x;
    sb[t] = (t < NBLK && t < b) ? bsum[t] : 0;
    __syncthreads();
    for (int off = 128; off > 0; off >>= 1) {
        if (t < off) sb[t] += sb[t + off];
        __syncthreads();
    }
    const int boff = sb[0];
    const int i = b * 256 + t;
    if (i < NN) {
        rptr[i] += boff;
        float degw = (float)(hist[i] & WMASK) * (1.0f / WSCALE);
        dinv[i] = rsqrtf(degw + 1.0f);   // +1 self-loop; always > 0
    }
    if (b == 0 && t == 0) rptr[NN] = NE; // total is a constant
}

// ---------------- fill CSR: no atomic — slot = rptr[c] + rank[e] ----------------
__global__ void fill_kernel(const int* __restrict__ ei, const float* __restrict__ ew,
                            const float* __restrict__ dinv, const int* __restrict__ rptr,
                            const int* __restrict__ rank, int2* __restrict__ csr) {
    int e = blockIdx.x * blockDim.x + threadIdx.x;
    if (e >= NE) return;
    int r = ei[e], c = ei[NE + e];
    int slot = rptr[c] + rank[e];
    float w = dinv[r] * ew[e] * dinv[c];
    csr[slot] = make_int2(r, __float_as_int(w));
}

// ---------------- SpMM (bf16 gather, f32 accum, unroll-4) + fused BN partials ----------------
__global__ __launch_bounds__(256) void spmm_kernel(const int* __restrict__ rptr,
                                                   const int2* __restrict__ csr,
                                                   const unsigned short* __restrict__ Hb,
                                                   const float* __restrict__ dinv,
                                                   const float* __restrict__ bg,
                                                   float* __restrict__ OUT,
                                                   float* __restrict__ P) {
    const int nl = threadIdx.x >> 5;                 // node lane 0..7
    const int lane = threadIdx.x & 31;               // channel-group lane
    const int node = blockIdx.x * 8 + nl;            // NN == gridDim*8 exactly
    const int ch = lane * 4;
    int s = rptr[node], e = rptr[node + 1];
    float d = dinv[node];
    float dd = d * d;
    float4 h = bf4_to_f4(*(const uint2*)(Hb + (size_t)node * C + ch));
    float4 acc = make_float4(dd * h.x, dd * h.y, dd * h.z, dd * h.w);
    float4 accB = make_float4(0.f, 0.f, 0.f, 0.f);
    int j = s;
    for (; j + 4 <= e; j += 4) {
        int2 e0 = csr[j], e1 = csr[j + 1], e2 = csr[j + 2], e3 = csr[j + 3];
        float w0 = __int_as_float(e0.y), w1 = __int_as_float(e1.y);
        float w2 = __int_as_float(e2.y), w3 = __int_as_float(e3.y);
        uint2 u0 = *(const uint2*)(Hb + (size_t)e0.x * C + ch);
        uint2 u1 = *(const uint2*)(Hb + (size_t)e1.x * C + ch);
        uint2 u2 = *(const uint2*)(Hb + (size_t)e2.x * C + ch);
        uint2 u3 = *(const uint2*)(Hb + (size_t)e3.x * C + ch);
        float4 v0 = bf4_to_f4(u0), v1 = bf4_to_f4(u1), v2 = bf4_to_f4(u2), v3 = bf4_to_f4(u3);
        acc.x = fmaf(v0.x, w0, acc.x);  acc.y = fmaf(v0.y, w0, acc.y);
        acc.z = fmaf(v0.z, w0, acc.z);  acc.w = fmaf(v0.w, w0, acc.w);
        accB.x = fmaf(v1.x, w1, accB.x); accB.y = fmaf(v1.y, w1, accB.y);
        accB.z = fmaf(v1.z, w1, accB.z); accB.w = fmaf(v1.w, w1, accB.w);
        acc.x = fmaf(v2.x, w2, acc.x);  acc.y = fmaf(v2.y, w2, acc.y);
        acc.z = fmaf(v2.z, w2, acc.z);  acc.w = fmaf(v2.w, w2, acc.w);
        accB.x = fmaf(v3.x, w3, accB.x); accB.y = fmaf(v3.y, w3, accB.y);
        accB.z = fmaf(v3.z, w3, accB.z); accB.w = fmaf(v3.w, w3, accB.w);
    }
    for (; j < e; j++) {
        int2 e0 = csr[j];
        float w0 = __int_as_float(e0.y);
        float4 v0 = bf4_to_f4(*(const uint2*)(Hb + (size_t)e0.x * C + ch));
        acc.x = fmaf(v0.x, w0, acc.x); acc.y = fmaf(v0.y, w0, acc.y);
        acc.z = fmaf(v0.z, w0, acc.z); acc.w = fmaf(v0.w, w0, acc.w);
    }
    acc.x += accB.x; acc.y += accB.y; acc.z += accB.z; acc.w += accB.w;
    float4 b = *(const float4*)(bg + ch);
    acc.x += b.x; acc.y += b.y; acc.z += b.z; acc.w += b.w;
    *(float4*)(OUT + (size_t)node * C + ch) = acc;

    // ---- fused BN partials: reduce over the block's 8 nodes, no atomics ----
    __shared__ __align__(16) float4 sred[2][8][32];   // 8 KiB
    float4 sq = make_float4(acc.x * acc.x, acc.y * acc.y, acc.z * acc.z, acc.w * acc.w);
    sred[0][nl][lane] = acc;
    sred[1][nl][lane] = sq;
    __syncthreads();
    if (nl == 0) {
        float4 s0 = sred[0][0][lane], q0 = sred[1][0][lane];
#pragma unroll
        for (int k = 1; k < 8; k++) {
            float4 a = sred[0][k][lane];
            float4 q = sred[1][k][lane];
            s0.x += a.x; s0.y += a.y; s0.z += a.z; s0.w += a.w;
            q0.x += q.x; q0.y += q.y; q0.z += q.z; q0.w += q.w;
        }
        float* row = P + (size_t)blockIdx.x * 256;
        *(float4*)(row + ch) = s0;
        *(float4*)(row + 128 + ch) = q0;
    }
}

// ---------------- reduce1 + fused bnparam (last-block pattern) ----------------
__global__ __launch_bounds__(256) void reduce1_kernel(const float* __restrict__ P,
                                                      float* __restrict__ P2,
                                                      unsigned int* __restrict__ cnt,
                                                      const float* __restrict__ gm,
                                                      const float* __restrict__ bt,
                                                      float* __restrict__ sc,
                                                      float* __restrict__ sh) {
    const int c = threadIdx.x;
    const int r0 = blockIdx.x * RROWS;
    const int r1 = min(r0 + RROWS, SPB);
    float a0 = 0.f, a1 = 0.f, a2 = 0.f, a3 = 0.f;
    int r = r0;
    for (; r + 4 <= r1; r += 4) {
        a0 += P[(size_t)(r + 0) * 256 + c];
        a1 += P[(size_t)(r + 1) * 256 + c];
        a2 += P[(size_t)(r + 2) * 256 + c];
        a3 += P[(size_t)(r + 3) * 256 + c];
    }
    for (; r < r1; r++) a0 += P[(size_t)r * 256 + c];
    P2[(size_t)blockIdx.x * 256 + c] = (a0 + a1) + (a2 + a3);

    __threadfence();
    __shared__ unsigned int done;
    if (c == 0) done = atomicAdd(cnt, 1u);
    __syncthreads();
    if (done == RB - 1) {
        __threadfence();   // acquire: see all P2 rows
        if (c < 128) {
            float s0 = 0.f, s1 = 0.f, q0 = 0.f, q1 = 0.f;
            for (int k = 0; k < RB; k += 2) {
                s0 += P2[(size_t)k * 256 + c];
                q0 += P2[(size_t)k * 256 + 128 + c];
                s1 += P2[(size_t)(k + 1) * 256 + c];
                q1 += P2[(size_t)(k + 1) * 256 + 128 + c];
            }
            float ssum = s0 + s1, ssq = q0 + q1;
            float mean = ssum / (float)NN;
            float var = ssq / (float)NN - mean * mean;
            var = fmaxf(var, 0.f);
            float rs = rsqrtf(var + BN_EPS);
            float s = gm[c] * rs;
            sc[c] = s;
            sh[c] = bt[c] - mean * s;
        }
    }
}

// ---------------- final (MFMA, LDS-staged B): y = lrelu(BN(h)) @ W_lin + b_lin, in-place ----------------
// Each wave reads only its own 16 rows and writes only those rows -> in-place safe.
__global__ __launch_bounds__(256) void final_kernel(float* __restrict__ OUT,
                                                    const unsigned int* __restrict__ Wt,
                                                    const float* __restrict__ bl,
                                                    const float* __restrict__ sc,
                                                    const float* __restrict__ sh) {
    __shared__ unsigned int wsh[8192];   // 32 KB, swizzled [col][ku]
    const int t = threadIdx.x;
#pragma unroll
    for (int i = 0; i < 8; i++)
        ((uint4*)wsh)[t + i * 256] = ((const uint4*)Wt)[t + i * 256];

    const int lane = t & 63;
    const int wid = t >> 6;
    const int lrow = lane & 15;
    const int kb = lane >> 4;
    const int row = blockIdx.x * 64 + wid * 16 + lrow;
    const float* hrow = OUT + (size_t)min(row, NN - 1) * C;

    f32x4 acc[8];
#pragma unroll
    for (int n = 0; n < 8; n++) acc[n] = (f32x4){0.f, 0.f, 0.f, 0.f};
    __syncthreads();

#pragma unroll
    for (int ks = 0; ks < 4; ks++) {
        const int k0 = ks * 32 + kb * 8;
        float4 v0 = *(const float4*)(hrow + k0);
        float4 v1 = *(const float4*)(hrow + k0 + 4);
        float4 s0 = *(const float4*)(sc + k0);
        float4 s1 = *(const float4*)(sc + k0 + 4);
        float4 h0 = *(const float4*)(sh + k0);
        float4 h1 = *(const float4*)(sh + k0 + 4);
        float a[8];
        a[0] = fmaf(v0.x, s0.x, h0.x); a[1] = fmaf(v0.y, s0.y, h0.y);
        a[2] = fmaf(v0.z, s0.z, h0.z); a[3] = fmaf(v0.w, s0.w, h0.w);
        a[4] = fmaf(v1.x, s1.x, h1.x); a[5] = fmaf(v1.y, s1.y, h1.y);
        a[6] = fmaf(v1.z, s1.z, h1.z); a[7] = fmaf(v1.w, s1.w, h1.w);
#pragma unroll
        for (int i = 0; i < 8; i++) a[i] = a[i] >= 0.f ? a[i] : NEG * a[i];
        union { unsigned int u[4]; bf16x8 v; } af;
        af.u[0] = pack2(a[0], a[1]); af.u[1] = pack2(a[2], a[3]);
        af.u[2] = pack2(a[4], a[5]); af.u[3] = pack2(a[6], a[7]);
        const unsigned int gp = (unsigned int)((ks * 4 + kb) ^ lrow);
#pragma unroll
        for (int n = 0; n < 8; n++) {
            int col = n * 16 + lrow;
            union { uint4 q; bf16x8 v; } bfm;
            bfm.q = *(const uint4*)&wsh[col * 64 + gp * 4];
            acc[n] = __builtin_amdgcn_mfma_f32_16x16x32_bf16(af.v, bfm.v, acc[n], 0, 0, 0);
        }
    }
    const int orow = blockIdx.x * 64 + wid * 16 + kb * 4;
#pragma unroll
    for (int n = 0; n < 8; n++) {
        int col = n * 16 + lrow;
        float blv = bl[col];
#pragma unroll
        for (int i = 0; i < 4; i++) {
            int r = orow + i;
            if (r < NN) OUT[(size_t)r * C + col] = acc[n][i] + blv;
        }
    }
}

extern "C" void kernel_launch(void* const* d_in, const int* in_sizes, int n_in,
                              void* d_out, int out_size, void* d_ws, size_t ws_size,
                              hipStream_t stream) {
    const float* x  = (const float*)d_in[0];
    const int*   ei = (const int*)d_in[1];
    const float* ew = (const float*)d_in[2];
    const float* td = (const float*)d_in[3];
    const float* mf = (const float*)d_in[4];
    const float* Wg = (const float*)d_in[5];
    const float* bg = (const float*)d_in[6];
    const float* gm = (const float*)d_in[7];
    const float* bt = (const float*)d_in[8];
    const float* Wl = (const float*)d_in[9];
    const float* bl = (const float*)d_in[10];
    float* out = (float*)d_out;

    // workspace layout (all chunk sizes are multiples of 16 B)
    unsigned short* h1b = (unsigned short*)d_ws;         // NN*C bf16 (12.8 MB)
    unsigned long long* hist = (unsigned long long*)(h1b + (size_t)NN * C);  // NN u64 [zeroed]
    unsigned int* cnt = (unsigned int*)(hist + NN);      // 4 u32 [zeroed]
    float* dinv   = (float*)(cnt + 4);                   // NN
    float* cvec   = dinv + NN;                           // C
    float* sc     = cvec + C;                            // C
    float* sh     = sc + C;                              // C
    int*   rptr   = (int*)(sh + C);                      // NN+8
    int*   bsum   = rptr + NN + 8;                       // 196 (+pad)
    int*   rank   = bsum + NBLK + 12;                    // NE
    int2*  csr    = (int2*)(rank + NE);                  // NE int2
    float* P      = (float*)(csr + NE);                  // SPB*256 (6.4 MB)
    float* P2     = P + (size_t)SPB * 256;               // RB*256
    unsigned int* Wgt = (unsigned int*)(P2 + RB * 256);  // 8192 u32 (32 KB)
    unsigned int* Wlt = Wgt + 8192;                      // 8192 u32 (32 KB)

    setup_kernel<<<130, 256, 0, stream>>>(Wg, Wl, Wgt, Wlt, td, mf, cvec, (float*)hist);
    hist_kernel<<<HISTB, 256, 0, stream>>>(ei, ew, hist, rank);
    gemm1_kernel<<<GB, 256, 0, stream>>>(x, Wgt, cvec, h1b);
    scanp1_kernel<<<NBLK, 256, 0, stream>>>(hist, rptr, bsum);
    scanp3_kernel<<<NBLK, 256, 0, stream>>>(rptr, bsum, hist, dinv);
    fill_kernel<<<HISTB, 256, 0, stream>>>(ei, ew, dinv, rptr, rank, csr);
    spmm_kernel<<<SPB, 256, 0, stream>>>(rptr, csr, h1b, dinv, bg, out, P);
    reduce1_kernel<<<RB, 256, 0, stream>>>(P, P2, cnt, gm, bt, sc, sh);
    final_kernel<<<GB, 256, 0, stream>>>(out, Wlt, bl, sc, sh);
}

// Round 11
// 142.704 us; speedup vs baseline: 1.1241x; 1.0220x over previous
//
#include <hip/hip_runtime.h>
#include <hip/hip_bf16.h>

#define NN 50000
#define NE 500000
#define C 128
#define NBLK ((NN + 255) / 256)       // 196 scan blocks
#define HISTB ((NE + 255) / 256)      // 1954 hist blocks
#define SPB2 (NN / 16)                // 3125 spmm blocks (exact: 50000 = 3125*16)
#define RB 128                        // reduce1 blocks
#define RROWS ((SPB2 + RB - 1) / RB)  // 25 rows per reduce1 block
#define GB ((NN + 63) / 64)           // 782 gemm blocks
#define BN_EPS 1e-5f
#define NEG 0.01f
#define WSCALE 16777216.0f            // 2^24 fixed-point for packed degree
#define WMASK  0xFFFFFFFFFFFULL      // low 44 bits

typedef __attribute__((ext_vector_type(8))) short bf16x8;
typedef __attribute__((ext_vector_type(4))) float f32x4;
typedef unsigned long long ull;

// bf16 helpers
__device__ inline unsigned short f2bf(float f) {            // round-to-nearest-even
    unsigned int u = __float_as_uint(f);
    unsigned int r = (u + 0x7fffu + ((u >> 16) & 1u)) >> 16;
    return (unsigned short)r;
}
__device__ inline unsigned int pack2(float a, float b) {
    return (unsigned int)f2bf(a) | ((unsigned int)f2bf(b) << 16);
}
__device__ inline float4 bf4_to_f4(unsigned int lo, unsigned int hi) {  // 4 packed bf16 -> f32
    float4 r;
    r.x = __uint_as_float(lo << 16);
    r.y = __uint_as_float(lo & 0xffff0000u);
    r.z = __uint_as_float(hi << 16);
    r.w = __uint_as_float(hi & 0xffff0000u);
    return r;
}

// ---------------- setup: zero hist+cnt+bflag | wprep (swizzled) | cvec ----------------
__global__ __launch_bounds__(256) void setup_kernel(const float* __restrict__ Wg,
                                                    const float* __restrict__ Wl,
                                                    unsigned int* __restrict__ Wgt,
                                                    unsigned int* __restrict__ Wlt,
                                                    const float* __restrict__ td,
                                                    const float* __restrict__ mf,
                                                    float* __restrict__ cvec,
                                                    float* __restrict__ zreg) {
    const int b = blockIdx.x;
    const int t = threadIdx.x;
    if (b < 128) {
        long i = (long)b * 256 + t;
        const long n = 2L * NN + 516;      // hist (NN u64) + cnt (4 u32) + bflag (256 u64)
        const long s = 128L * 256;
        for (; i < n; i += s) zreg[i] = 0.f;
    } else if (b == 128) {
        // W[k][c] f32 -> Wt[c][ku] bf16 pairs, 16B-granule XOR swizzle (for LDS b128 reads)
        const int col = t >> 1;
        const int half = t & 1;
        for (int j = 0; j < 32; j++) {
            int ku = half * 32 + j;
            int k0 = 2 * ku;
            unsigned int g = (unsigned int)((ku >> 2) ^ (col & 15));
            unsigned int slot = (unsigned int)col * 64u + (g << 2) + (unsigned int)(ku & 3);
            Wgt[slot] = pack2(Wg[(size_t)k0 * C + col], Wg[(size_t)(k0 + 1) * C + col]);
            Wlt[slot] = pack2(Wl[(size_t)k0 * C + col], Wl[(size_t)(k0 + 1) * C + col]);
        }
    } else {
        if (t < 128) {
            float tv = td[0];
            float acc = 0.f;
#pragma unroll
            for (int j = 0; j < 16; j++) {
                float s = sinf(tv * mf[j] * 3.14159265358979323846f);
                acc = fmaf(s, Wg[(128 + j) * C + t], acc);
            }
            cvec[t] = acc;
        }
    }
}

// ---------------- packed histogram + per-edge rank ----------------
__global__ void hist_kernel(const int* __restrict__ ei, const float* __restrict__ ew,
                            ull* __restrict__ hist, int* __restrict__ rank) {
    int e = blockIdx.x * blockDim.x + threadIdx.x;
    if (e < NE) {
        int c = ei[NE + e];
        ull pack = (1ULL << 44) | (ull)(ew[e] * WSCALE);
        ull old = atomicAdd(&hist[c], pack);
        rank[e] = (int)(old >> 44);
    }
}

// ---------------- GEMM1 (MFMA, LDS-staged B): h1b = bf16(x @ Wg[0:128,:] + cvec) ----------------
__global__ __launch_bounds__(256) void gemm1_kernel(const float* __restrict__ X,
                                                    const unsigned int* __restrict__ Wt,
                                                    const float* __restrict__ cvec,
                                                    unsigned short* __restrict__ Hb) {
    __shared__ unsigned int wsh[8192];   // 32 KB, swizzled [col][ku]
    const int t = threadIdx.x;
#pragma unroll
    for (int i = 0; i < 8; i++)
        ((uint4*)wsh)[t + i * 256] = ((const uint4*)Wt)[t + i * 256];

    const int lane = t & 63;
    const int wid = t >> 6;
    const int lrow = lane & 15;
    const int kb = lane >> 4;            // 0..3
    const int row = blockIdx.x * 64 + wid * 16 + lrow;
    const float* xrow = X + (size_t)min(row, NN - 1) * C;

    f32x4 acc[8];
#pragma unroll
    for (int n = 0; n < 8; n++) acc[n] = (f32x4){0.f, 0.f, 0.f, 0.f};
    __syncthreads();

#pragma unroll
    for (int ks = 0; ks < 4; ks++) {
        float4 a0 = *(const float4*)(xrow + ks * 32 + kb * 8);
        float4 a1 = *(const float4*)(xrow + ks * 32 + kb * 8 + 4);
        union { unsigned int u[4]; bf16x8 v; } af;
        af.u[0] = pack2(a0.x, a0.y); af.u[1] = pack2(a0.z, a0.w);
        af.u[2] = pack2(a1.x, a1.y); af.u[3] = pack2(a1.z, a1.w);
        const unsigned int gp = (unsigned int)((ks * 4 + kb) ^ lrow);
#pragma unroll
        for (int n = 0; n < 8; n++) {
            int col = n * 16 + lrow;
            union { uint4 q; bf16x8 v; } bfm;
            bfm.q = *(const uint4*)&wsh[col * 64 + gp * 4];
            acc[n] = __builtin_amdgcn_mfma_f32_16x16x32_bf16(af.v, bfm.v, acc[n], 0, 0, 0);
        }
    }
    const int orow = blockIdx.x * 64 + wid * 16 + kb * 4;   // C/D: col=lane&15, row=(lane>>4)*4+i
#pragma unroll
    for (int n = 0; n < 8; n++) {
        int col = n * 16 + lrow;
        float cv = cvec[col];
#pragma unroll
        for (int i = 0; i < 4; i++) {
            int r = orow + i;
            if (r < NN) Hb[(size_t)r * C + col] = f2bf(acc[n][i] + cv);
        }
    }
}

// ---------------- fused scan: per-block scan + publish + lookback + dinv ----------------
__global__ __launch_bounds__(256) void scan_kernel(const ull* __restrict__ hist,
                                                   int* __restrict__ rptr,
                                                   float* __restrict__ dinv,
                                                   ull* __restrict__ bflag) {
    __shared__ int s[256];
    __shared__ int pre[256];
    const int t = threadIdx.x;
    const int b = blockIdx.x;
    const int i = b * 256 + t;
    ull hv = (i < NN) ? hist[i] : 0ULL;
    int v = (int)(hv >> 44);
    s[t] = v;
    __syncthreads();
    for (int off = 1; off < 256; off <<= 1) {
        int add = (t >= off) ? s[t - off] : 0;
        __syncthreads();
        s[t] += add;
        __syncthreads();
    }
    // publish inclusive block total (flag in bit 32)
    if (t == 255)
        __hip_atomic_store(&bflag[b], (1ULL << 32) | (ull)(unsigned int)s[255],
                           __ATOMIC_RELEASE, __HIP_MEMORY_SCOPE_AGENT);
    // lookback: thread t (< b) grabs block t's total; all 196 blocks co-resident (256 CUs)
    int pv = 0;
    if (t < b) {
        ull f;
        do {
            f = __hip_atomic_load(&bflag[t], __ATOMIC_ACQUIRE, __HIP_MEMORY_SCOPE_AGENT);
        } while (!(f >> 32));
        pv = (int)(unsigned int)f;
    }
    pre[t] = pv;
    __syncthreads();
    for (int off = 128; off > 0; off >>= 1) {
        if (t < off) pre[t] += pre[t + off];
        __syncthreads();
    }
    const int boff = pre[0];
    if (i < NN) {
        rptr[i] = boff + s[t] - v;                      // global exclusive prefix
        float degw = (float)(hv & WMASK) * (1.0f / WSCALE);
        dinv[i] = rsqrtf(degw + 1.0f);                  // +1 self-loop; always > 0
    }
    if (b == 0 && t == 0) rptr[NN] = NE;                // total is a constant
}

// ---------------- fill CSR: no atomic — slot = rptr[c] + rank[e] ----------------
__global__ void fill_kernel(const int* __restrict__ ei, const float* __restrict__ ew,
                            const float* __restrict__ dinv, const int* __restrict__ rptr,
                            const int* __restrict__ rank, int2* __restrict__ csr) {
    int e = blockIdx.x * blockDim.x + threadIdx.x;
    if (e >= NE) return;
    int r = ei[e], c = ei[NE + e];
    int slot = rptr[c] + rank[e];
    float w = dinv[r] * ew[e] * dinv[c];
    csr[slot] = make_int2(r, __float_as_int(w));
}

// ---------------- SpMM v2: 16 lanes/node, uint4 gathers, bf16 out + fused BN partials ----------------
__global__ __launch_bounds__(256) void spmm_kernel(const int* __restrict__ rptr,
                                                   const int2* __restrict__ csr,
                                                   const unsigned short* __restrict__ Hb,
                                                   const float* __restrict__ dinv,
                                                   const float* __restrict__ bg,
                                                   unsigned short* __restrict__ H2,
                                                   float* __restrict__ P) {
    const int t = threadIdx.x;
    const int nl = t >> 4;                           // node lane 0..15
    const int lane = t & 15;                         // channel-group lane
    const int node = blockIdx.x * 16 + nl;           // NN == gridDim*16 exactly
    const int ch = lane * 8;
    const int s = rptr[node], e = rptr[node + 1];
    const float d = dinv[node];
    const float dd = d * d;
    uint4 hu = *(const uint4*)(Hb + (size_t)node * C + ch);
    float4 hA = bf4_to_f4(hu.x, hu.y), hB = bf4_to_f4(hu.z, hu.w);
    float4 aA = make_float4(dd * hA.x, dd * hA.y, dd * hA.z, dd * hA.w);
    float4 aB = make_float4(dd * hB.x, dd * hB.y, dd * hB.z, dd * hB.w);
    float4 bA = make_float4(0.f, 0.f, 0.f, 0.f);
    float4 bB = make_float4(0.f, 0.f, 0.f, 0.f);
    int j = s;
    for (; j + 4 <= e; j += 4) {
        int2 m0 = csr[j], m1 = csr[j + 1], m2 = csr[j + 2], m3 = csr[j + 3];
        uint4 u0 = *(const uint4*)(Hb + (size_t)m0.x * C + ch);
        uint4 u1 = *(const uint4*)(Hb + (size_t)m1.x * C + ch);
        uint4 u2 = *(const uint4*)(Hb + (size_t)m2.x * C + ch);
        uint4 u3 = *(const uint4*)(Hb + (size_t)m3.x * C + ch);
        float w0 = __int_as_float(m0.y), w1 = __int_as_float(m1.y);
        float w2 = __int_as_float(m2.y), w3 = __int_as_float(m3.y);
        float4 vA, vB;
        vA = bf4_to_f4(u0.x, u0.y); vB = bf4_to_f4(u0.z, u0.w);
        aA.x = fmaf(vA.x, w0, aA.x); aA.y = fmaf(vA.y, w0, aA.y);
        aA.z = fmaf(vA.z, w0, aA.z); aA.w = fmaf(vA.w, w0, aA.w);
        aB.x = fmaf(vB.x, w0, aB.x); aB.y = fmaf(vB.y, w0, aB.y);
        aB.z = fmaf(vB.z, w0, aB.z); aB.w = fmaf(vB.w, w0, aB.w);
        vA = bf4_to_f4(u1.x, u1.y); vB = bf4_to_f4(u1.z, u1.w);
        bA.x = fmaf(vA.x, w1, bA.x); bA.y = fmaf(vA.y, w1, bA.y);
        bA.z = fmaf(vA.z, w1, bA.z); bA.w = fmaf(vA.w, w1, bA.w);
        bB.x = fmaf(vB.x, w1, bB.x); bB.y = fmaf(vB.y, w1, bB.y);
        bB.z = fmaf(vB.z, w1, bB.z); bB.w = fmaf(vB.w, w1, bB.w);
        vA = bf4_to_f4(u2.x, u2.y); vB = bf4_to_f4(u2.z, u2.w);
        aA.x = fmaf(vA.x, w2, aA.x); aA.y = fmaf(vA.y, w2, aA.y);
        aA.z = fmaf(vA.z, w2, aA.z); aA.w = fmaf(vA.w, w2, aA.w);
        aB.x = fmaf(vB.x, w2, aB.x); aB.y = fmaf(vB.y, w2, aB.y);
        aB.z = fmaf(vB.z, w2, aB.z); aB.w = fmaf(vB.w, w2, aB.w);
        vA = bf4_to_f4(u3.x, u3.y); vB = bf4_to_f4(u3.z, u3.w);
        bA.x = fmaf(vA.x, w3, bA.x); bA.y = fmaf(vA.y, w3, bA.y);
        bA.z = fmaf(vA.z, w3, bA.z); bA.w = fmaf(vA.w, w3, bA.w);
        bB.x = fmaf(vB.x, w3, bB.x); bB.y = fmaf(vB.y, w3, bB.y);
        bB.z = fmaf(vB.z, w3, bB.z); bB.w = fmaf(vB.w, w3, bB.w);
    }
    for (; j < e; j++) {
        int2 m0 = csr[j];
        uint4 u0 = *(const uint4*)(Hb + (size_t)m0.x * C + ch);
        float w0 = __int_as_float(m0.y);
        float4 vA = bf4_to_f4(u0.x, u0.y), vB = bf4_to_f4(u0.z, u0.w);
        aA.x = fmaf(vA.x, w0, aA.x); aA.y = fmaf(vA.y, w0, aA.y);
        aA.z = fmaf(vA.z, w0, aA.z); aA.w = fmaf(vA.w, w0, aA.w);
        aB.x = fmaf(vB.x, w0, aB.x); aB.y = fmaf(vB.y, w0, aB.y);
        aB.z = fmaf(vB.z, w0, aB.z); aB.w = fmaf(vB.w, w0, aB.w);
    }
    aA.x += bA.x; aA.y += bA.y; aA.z += bA.z; aA.w += bA.w;
    aB.x += bB.x; aB.y += bB.y; aB.z += bB.z; aB.w += bB.w;
    float4 g0 = *(const float4*)(bg + ch);
    float4 g1 = *(const float4*)(bg + ch + 4);
    aA.x += g0.x; aA.y += g0.y; aA.z += g0.z; aA.w += g0.w;
    aB.x += g1.x; aB.y += g1.y; aB.z += g1.z; aB.w += g1.w;
    // store h2 as bf16 (final re-rounds to bf16 for MFMA anyway)
    uint4 ou;
    ou.x = pack2(aA.x, aA.y); ou.y = pack2(aA.z, aA.w);
    ou.z = pack2(aB.x, aB.y); ou.w = pack2(aB.z, aB.w);
    *(uint4*)(H2 + (size_t)node * C + ch) = ou;

    // ---- fused BN partials over the block's 16 nodes (f32, pre-rounding) ----
    __shared__ float sred[2][16][128];   // 16 KiB
    *(float4*)&sred[0][nl][ch]     = aA;
    *(float4*)&sred[0][nl][ch + 4] = aB;
    float4 qA = make_float4(aA.x * aA.x, aA.y * aA.y, aA.z * aA.z, aA.w * aA.w);
    float4 qB = make_float4(aB.x * aB.x, aB.y * aB.y, aB.z * aB.z, aB.w * aB.w);
    *(float4*)&sred[1][nl][ch]     = qA;
    *(float4*)&sred[1][nl][ch + 4] = qB;
    __syncthreads();
    const int q = t >> 7, c2 = t & 127;
    float acc = 0.f;
#pragma unroll
    for (int k = 0; k < 16; k++) acc += sred[q][k][c2];
    P[(size_t)blockIdx.x * 256 + t] = acc;   // [0:128]=sum, [128:256]=sumsq
}

// ---------------- reduce1 + fused bnparam (last-block pattern) ----------------
__global__ __launch_bounds__(256) void reduce1_kernel(const float* __restrict__ P,
                                                      float* __restrict__ P2,
                                                      unsigned int* __restrict__ cnt,
                                                      const float* __restrict__ gm,
                                                      const float* __restrict__ bt,
                                                      float* __restrict__ sc,
                                                      float* __restrict__ sh) {
    const int c = threadIdx.x;
    const int r0 = blockIdx.x * RROWS;
    const int r1 = min(r0 + RROWS, SPB2);
    float a0 = 0.f, a1 = 0.f, a2 = 0.f, a3 = 0.f;
    int r = r0;
    for (; r + 4 <= r1; r += 4) {
        a0 += P[(size_t)(r + 0) * 256 + c];
        a1 += P[(size_t)(r + 1) * 256 + c];
        a2 += P[(size_t)(r + 2) * 256 + c];
        a3 += P[(size_t)(r + 3) * 256 + c];
    }
    for (; r < r1; r++) a0 += P[(size_t)r * 256 + c];
    P2[(size_t)blockIdx.x * 256 + c] = (a0 + a1) + (a2 + a3);

    __threadfence();
    __shared__ unsigned int done;
    if (c == 0) done = atomicAdd(cnt, 1u);
    __syncthreads();
    if (done == RB - 1) {
        __threadfence();   // acquire: see all P2 rows
        if (c < 128) {
            float s0 = 0.f, s1 = 0.f, q0 = 0.f, q1 = 0.f;
            for (int k = 0; k < RB; k += 2) {
                s0 += P2[(size_t)k * 256 + c];
                q0 += P2[(size_t)k * 256 + 128 + c];
                s1 += P2[(size_t)(k + 1) * 256 + c];
                q1 += P2[(size_t)(k + 1) * 256 + 128 + c];
            }
            float ssum = s0 + s1, ssq = q0 + q1;
            float mean = ssum / (float)NN;
            float var = ssq / (float)NN - mean * mean;
            var = fmaxf(var, 0.f);
            float rs = rsqrtf(var + BN_EPS);
            float s = gm[c] * rs;
            sc[c] = s;
            sh[c] = bt[c] - mean * s;
        }
    }
}

// ---------------- final (MFMA, LDS-staged B): y = lrelu(BN(h2)) @ W_lin + b_lin ----------------
__global__ __launch_bounds__(256) void final_kernel(const unsigned short* __restrict__ H2,
                                                    float* __restrict__ OUT,
                                                    const unsigned int* __restrict__ Wt,
                                                    const float* __restrict__ bl,
                                                    const float* __restrict__ sc,
                                                    const float* __restrict__ sh) {
    __shared__ unsigned int wsh[8192];   // 32 KB, swizzled [col][ku]
    const int t = threadIdx.x;
#pragma unroll
    for (int i = 0; i < 8; i++)
        ((uint4*)wsh)[t + i * 256] = ((const uint4*)Wt)[t + i * 256];

    const int lane = t & 63;
    const int wid = t >> 6;
    const int lrow = lane & 15;
    const int kb = lane >> 4;
    const int row = blockIdx.x * 64 + wid * 16 + lrow;
    const unsigned short* hrow = H2 + (size_t)min(row, NN - 1) * C;

    f32x4 acc[8];
#pragma unroll
    for (int n = 0; n < 8; n++) acc[n] = (f32x4){0.f, 0.f, 0.f, 0.f};
    __syncthreads();

#pragma unroll
    for (int ks = 0; ks < 4; ks++) {
        const int k0 = ks * 32 + kb * 8;
        uint4 hu = *(const uint4*)(hrow + k0);
        float4 v0 = bf4_to_f4(hu.x, hu.y);
        float4 v1 = bf4_to_f4(hu.z, hu.w);
        float4 s0 = *(const float4*)(sc + k0);
        float4 s1 = *(const float4*)(sc + k0 + 4);
        float4 h0 = *(const float4*)(sh + k0);
        float4 h1 = *(const float4*)(sh + k0 + 4);
        float a[8];
        a[0] = fmaf(v0.x, s0.x, h0.x); a[1] = fmaf(v0.y, s0.y, h0.y);
        a[2] = fmaf(v0.z, s0.z, h0.z); a[3] = fmaf(v0.w, s0.w, h0.w);
        a[4] = fmaf(v1.x, s1.x, h1.x); a[5] = fmaf(v1.y, s1.y, h1.y);
        a[6] = fmaf(v1.z, s1.z, h1.z); a[7] = fmaf(v1.w, s1.w, h1.w);
#pragma unroll
        for (int i = 0; i < 8; i++) a[i] = a[i] >= 0.f ? a[i] : NEG * a[i];
        union { unsigned int u[4]; bf16x8 v; } af;
        af.u[0] = pack2(a[0], a[1]); af.u[1] = pack2(a[2], a[3]);
        af.u[2] = pack2(a[4], a[5]); af.u[3] = pack2(a[6], a[7]);
        const unsigned int gp = (unsigned int)((ks * 4 + kb) ^ lrow);
#pragma unroll
        for (int n = 0; n < 8; n++) {
            int col = n * 16 + lrow;
            union { uint4 q; bf16x8 v; } bfm;
            bfm.q = *(const uint4*)&wsh[col * 64 + gp * 4];
            acc[n] = __builtin_amdgcn_mfma_f32_16x16x32_bf16(af.v, bfm.v, acc[n], 0, 0, 0);
        }
    }
    const int orow = blockIdx.x * 64 + wid * 16 + kb * 4;
#pragma unroll
    for (int n = 0; n < 8; n++) {
        int col = n * 16 + lrow;
        float blv = bl[col];
#pragma unroll
        for (int i = 0; i < 4; i++) {
            int r = orow + i;
            if (r < NN) OUT[(size_t)r * C + col] = acc[n][i] + blv;
        }
    }
}

extern "C" void kernel_launch(void* const* d_in, const int* in_sizes, int n_in,
                              void* d_out, int out_size, void* d_ws, size_t ws_size,
                              hipStream_t stream) {
    const float* x  = (const float*)d_in[0];
    const int*   ei = (const int*)d_in[1];
    const float* ew = (const float*)d_in[2];
    const float* td = (const float*)d_in[3];
    const float* mf = (const float*)d_in[4];
    const float* Wg = (const float*)d_in[5];
    const float* bg = (const float*)d_in[6];
    const float* gm = (const float*)d_in[7];
    const float* bt = (const float*)d_in[8];
    const float* Wl = (const float*)d_in[9];
    const float* bl = (const float*)d_in[10];
    float* out = (float*)d_out;

    // workspace layout (all chunk offsets 16B-aligned)
    unsigned short* h1b = (unsigned short*)d_ws;         // NN*C bf16 (12.8 MB)
    unsigned short* h2b = h1b + (size_t)NN * C;          // NN*C bf16 (12.8 MB)
    ull*   hist  = (ull*)(h2b + (size_t)NN * C);         // NN u64 [zeroed]
    unsigned int* cnt = (unsigned int*)(hist + NN);      // 4 u32 [zeroed]
    ull*   bflag = (ull*)(cnt + 4);                      // 256 u64 [zeroed]
    float* dinv  = (float*)(bflag + 256);                // NN
    float* cvec  = dinv + NN;                            // C
    float* sc    = cvec + C;                             // C
    float* sh    = sc + C;                               // C
    int*   rptr  = (int*)(sh + C);                       // NN+8
    int*   rank  = rptr + NN + 8;                        // NE
    int2*  csr   = (int2*)(rank + NE);                   // NE int2
    float* P     = (float*)(csr + NE);                   // SPB2*256 (3.2 MB)
    float* P2    = P + (size_t)SPB2 * 256;               // RB*256
    unsigned int* Wgt = (unsigned int*)(P2 + RB * 256);  // 8192 u32 (32 KB)
    unsigned int* Wlt = Wgt + 8192;                      // 8192 u32 (32 KB)

    setup_kernel<<<130, 256, 0, stream>>>(Wg, Wl, Wgt, Wlt, td, mf, cvec, (float*)hist);
    hist_kernel<<<HISTB, 256, 0, stream>>>(ei, ew, hist, rank);
    gemm1_kernel<<<GB, 256, 0, stream>>>(x, Wgt, cvec, h1b);
    scan_kernel<<<NBLK, 256, 0, stream>>>(hist, rptr, dinv, bflag);
    fill_kernel<<<HISTB, 256, 0, stream>>>(ei, ew, dinv, rptr, rank, csr);
    spmm_kernel<<<SPB2, 256, 0, stream>>>(rptr, csr, h1b, dinv, bg, h2b, P);
    reduce1_kernel<<<RB, 256, 0, stream>>>(P, P2, cnt, gm, bt, sc, sh);
    final_kernel<<<GB, 256, 0, stream>>>(h2b, out, Wlt, bl, sc, sh);
}